// Round 1
// 1378.085 us; speedup vs baseline: 1.0071x; 1.0071x over previous
//
#include <hip/hip_runtime.h>

typedef __attribute__((ext_vector_type(8))) short short8;
typedef __attribute__((ext_vector_type(4))) float f32x4;
typedef unsigned short u16;

__device__ __forceinline__ unsigned short f2bf(float f) {
  union { float f; unsigned u; } v; v.f = f;
  unsigned r = v.u + 0x7fffu + ((v.u >> 16) & 1u);
  return (unsigned short)(r >> 16);
}
__device__ __forceinline__ unsigned pack2bf(float lo, float hi) {
  return (unsigned)f2bf(lo) | ((unsigned)f2bf(hi) << 16);
}
__device__ __forceinline__ float sigm(float x) { return 1.0f / (1.0f + __expf(-x)); }
__device__ __forceinline__ float tanh_fast(float x) { return 1.0f - 2.0f / (__expf(2.0f * x) + 1.0f); }

// ---------- fp32 -> bf16 convert + pack into MFMA-fragment order ----------
// packed blob: [tile16][kstep32][lane64][8]; lane = (row&15) + 16*((k>>3)&3).
// One "pk block" = 8 rows x 1024 cols of the source.
__device__ __forceinline__ void cvt_body(const float* __restrict__ src,
                                         uint4* __restrict__ dst,
                                         int lb, int ns, int klog,
                                         u16 (*lds)[1032]) {
  int ht = lb / ns, span = lb - ht * ns;
  long row0 = (long)ht * 8;
  int c0 = span << 10;

  const int tr = threadIdx.x >> 5, tc = threadIdx.x & 31;
  const float* srow = src + ((row0 + tr) << klog) + c0;
#pragma unroll
  for (int p = 0; p < 8; ++p) {
    int col = p * 128 + tc * 4;
    float4 v = *(const float4*)(srow + col);
    *(uint2*)&lds[tr][col] = make_uint2(pack2bf(v.x, v.y), pack2bf(v.z, v.w));
  }
  __syncthreads();
  int tile = ht >> 1, h0 = (ht & 1) * 8;
  long ks = 1l << (klog - 5);
  uint4* dbase = dst + ((long)tile * ks + span * 32) * 64 + h0;
#pragma unroll
  for (int i = 0; i < 4; ++i) {
    int ci = threadIdx.x + 256 * i;
    int rr = ci & 7, kgrp = (ci >> 3) & 3, kstep = ci >> 5;
    dbase[(long)kstep * 64 + rr + 16 * kgrp] = *(const uint4*)&lds[rr][kstep * 32 + kgrp * 8];
  }
}

#define NPK 12
struct PKArgs {
  const float* src[NPK];
  uint4* dst[NPK];
  int cum[NPK + 1];
  int nspan[NPK];
  int klog[NPK];
};

__global__ __launch_bounds__(256) void cvt_pack(PKArgs a) {
  __shared__ __align__(16) u16 lds[8][1032];
  int b = blockIdx.x;
  int r = 0;
  while (b >= a.cum[r + 1]) ++r;
  cvt_body(a.src[r], a.dst[r], b - a.cum[r], a.nspan[r], a.klog[r], lds);
}

// ---------- pipelined dual-mtile K-segment: 4-kstep groups, double-buffered ----
// REQUIRES (se-sb) to be a multiple of 8 (pairs of groups, unconditional MMG(1)).
__device__ __forceinline__ void seg_mm(
    const short8* __restrict__ ap, const short8* __restrict__ wp, int ks,
    int sb, int se, f32x4& acc0, f32x4& acc1)
{
  if (sb >= se) return;
  short8 xa0[4], xb0[4], wv0[4], xa1[4], xb1[4], wv1[4];
#define LDG(B, S) { _Pragma("unroll") for (int d = 0; d < 4; ++d) { \
    xa##B[d] = ap[(long)((S) + d) * 64]; \
    xb##B[d] = ap[(long)(ks + (S) + d) * 64]; \
    wv##B[d] = wp[(long)((S) + d) * 64]; } }
#define MMG(B) { _Pragma("unroll") for (int d = 0; d < 4; ++d) { \
    acc0 = __builtin_amdgcn_mfma_f32_16x16x32_bf16(xa##B[d], wv##B[d], acc0, 0, 0, 0); \
    acc1 = __builtin_amdgcn_mfma_f32_16x16x32_bf16(xb##B[d], wv##B[d], acc1, 0, 0, 0); } }
  int s = sb;
  const int ng = (se - sb) >> 2;
  LDG(0, s)
  for (int g = 0; g < ng; g += 2) {
    LDG(1, s + 4)
    __builtin_amdgcn_sched_barrier(0);
    MMG(0)
    if (g + 2 < ng) LDG(0, s + 8)
    __builtin_amdgcn_sched_barrier(0);
    MMG(1)
    s += 8;
  }
#undef LDG
#undef MMG
}

// ---------- xpre = X (SBxK packed) @ W (NxK packed)^T, fp32 out ----------
__global__ __launch_bounds__(256) void gemm_pre(
    const u16* __restrict__ A, const u16* __restrict__ W,
    float* __restrict__ C, int N, int K)
{
  const int ks = K >> 5;
  const int m0 = blockIdx.x * 64;
  const int n0 = blockIdx.y * 64;
  const int w = threadIdx.x >> 6;
  const int lane = threadIdx.x & 63;
  const int colr = lane & 15;
  const int kgrp = lane >> 4;
  f32x4 acc[4] = {{0.f,0.f,0.f,0.f},{0.f,0.f,0.f,0.f},{0.f,0.f,0.f,0.f},{0.f,0.f,0.f,0.f}};
  const short8* ap = (const short8*)A + (long)(m0 / 16 + w) * ks * 64 + lane;
  const short8* wp = (const short8*)W + (long)(n0 / 16) * ks * 64 + lane;
  short8 av0[2], bv0[8], av1[2], bv1[8];
#define LDP(B, S) { _Pragma("unroll") for (int d = 0; d < 2; ++d) { \
    av##B[d] = ap[(long)((S) + d) * 64]; \
    _Pragma("unroll") for (int ct = 0; ct < 4; ++ct) \
      bv##B[ct * 2 + d] = wp[((long)ct * ks + (S) + d) * 64]; } }
#define MMP(B) { _Pragma("unroll") for (int d = 0; d < 2; ++d) \
    _Pragma("unroll") for (int ct = 0; ct < 4; ++ct) \
      acc[ct] = __builtin_amdgcn_mfma_f32_16x16x32_bf16(av##B[d], bv##B[ct * 2 + d], acc[ct], 0, 0, 0); }
  LDP(0, 0)
  for (int s = 0; s < ks; s += 4) {
    LDP(1, s + 2)
    __builtin_amdgcn_sched_barrier(0);
    MMP(0)
    if (s + 4 < ks) LDP(0, s + 4)
    __builtin_amdgcn_sched_barrier(0);
    MMP(1)
  }
#undef LDP
#undef MMP
#pragma unroll
  for (int ct = 0; ct < 4; ++ct)
#pragma unroll
    for (int j = 0; j < 4; ++j)
      C[(long)(m0 + w * 16 + kgrp * 4 + j) * N + n0 + ct * 16 + colr] = acc[ct][j];
}

// ---------- diagonal LSTM kernel: up to 3 independent cells per launch ----------
// Tail blocks (blockIdx.x >= lstm_blocks) run decoder-weight bf16 conversion,
// hiding the cvt traffic in the encoder launches' idle (latency-bound) cycles.
struct CellDesc {
  const u16 *A1, *W1, *A2, *W2;
  const float *pre, *bias;
  float *cbuf; u16 *hout; float *sigout;
  float *part; int *cnt;
  int K1, K2, dh, chunk, nslog, blkend;
};
struct PKRide {
  const float* src[5];
  uint4* dst[5];
  int cum[6];
  int nspan[5];
  int klog[5];
};
struct DiagArgs {
  CellDesc c[3];
  int ncell;
  int lstm_blocks;
  int ride_start, ride_count;
  PKRide ride;
};

__global__ __launch_bounds__(256) void lstm_diag(DiagArgs da) {
  __shared__ __align__(16) char smem[8 * 1032 * 2];   // union: cvt lds / ldsG
  int b = blockIdx.x;

  if (b >= da.lstm_blocks) {
    // conversion ride-along block
    int pb = b - da.lstm_blocks + da.ride_start;
    int r = 0;
    while (pb >= da.ride.cum[r + 1]) ++r;
    cvt_body(da.ride.src[r], da.ride.dst[r], pb - da.ride.cum[r],
             da.ride.nspan[r], da.ride.klog[r], (u16 (*)[1032])smem);
    return;
  }

  int ci = 0, bstart = 0;
  while (b >= da.c[ci].blkend) { bstart = da.c[ci].blkend; ++ci; }
  const CellDesc& cd = da.c[ci];
  const int local = b - bstart;
  const int nsplit = 1 << cd.nslog;
  const int tile = local >> cd.nslog;
  const int split = local & (nsplit - 1);
  const int g = threadIdx.x >> 6;
  const int lane = threadIdx.x & 63;
  const int colr = lane & 15;
  const int kgrp = lane >> 4;
  const int dh = cd.dh;
  const int dh16 = dh >> 4;
  const int K1 = cd.K1, K2 = cd.K2;

  f32x4 acc0 = {0.f, 0.f, 0.f, 0.f};
  f32x4 acc1 = {0.f, 0.f, 0.f, 0.f};
  const int kbeg = split * cd.chunk;
  const int kend = kbeg + cd.chunk;

  if (kbeg < K1) {
    const int e = kend < K1 ? kend : K1;
    const int ks = K1 >> 5;
    seg_mm((const short8*)cd.A1 + lane,
           (const short8*)cd.W1 + (long)(g * dh16 + tile) * ks * 64 + lane,
           ks, kbeg >> 5, e >> 5, acc0, acc1);
  }
  if (kend > K1 && K2 > 0) {
    const int b0 = kbeg > K1 ? kbeg : K1;
    const int ks = K2 >> 5;
    seg_mm((const short8*)cd.A2 + lane,
           (const short8*)cd.W2 + (long)(g * dh16 + tile) * ks * 64 + lane,
           ks, (b0 - K1) >> 5, (kend - K1) >> 5, acc0, acc1);
  }

  float (*ldsG)[16][33] = (float (*)[16][33])smem;
  {
    // Partials go to the coherent point via agent-scope atomic stores;
    // __syncthreads() drains vmcnt before tid0's cnt increment, so no
    // device-scope (L2-flushing) fence is needed.
    float* slot = cd.part + ((long)(tile * nsplit + split) * 4 + g) * 512 + colr * 32;
#pragma unroll
    for (int j = 0; j < 4; ++j) {
      __hip_atomic_store(&slot[kgrp * 4 + j],      acc0[j], __ATOMIC_RELAXED, __HIP_MEMORY_SCOPE_AGENT);
      __hip_atomic_store(&slot[16 + kgrp * 4 + j], acc1[j], __ATOMIC_RELAXED, __HIP_MEMORY_SCOPE_AGENT);
    }
    __threadfence_block();
    __shared__ int swin;
    __syncthreads();
    if (threadIdx.x == 0) swin = (atomicAdd(&cd.cnt[tile], 1) == nsplit - 1) ? 1 : 0;
    __syncthreads();
    if (!swin) return;
    __threadfence_block();
    for (int os = 0; os < nsplit; ++os) {
      if (os == split) continue;
      const float* oslot = cd.part + ((long)(tile * nsplit + os) * 4 + g) * 512 + colr * 32;
#pragma unroll
      for (int j = 0; j < 4; ++j) {
        acc0[j] += __hip_atomic_load(&oslot[kgrp * 4 + j],      __ATOMIC_RELAXED, __HIP_MEMORY_SCOPE_AGENT);
        acc1[j] += __hip_atomic_load(&oslot[16 + kgrp * 4 + j], __ATOMIC_RELAXED, __HIP_MEMORY_SCOPE_AGENT);
      }
    }
    if (threadIdx.x == 0) cd.cnt[tile] = 0;
  }

#pragma unroll
  for (int j = 0; j < 4; ++j) {
    ldsG[g][colr][kgrp * 4 + j] = acc0[j];
    ldsG[g][colr][16 + kgrp * 4 + j] = acc1[j];
  }
  __syncthreads();

  if (threadIdx.x < 64) {
    const int b2 = threadIdx.x >> 1;
    const int half = threadIdx.x & 1;
    const int u0l = half * 8;
    const int u0 = tile * 16 + u0l;
    float hv[8], cv[8], sv[8];
#pragma unroll
    for (int e = 0; e < 8; ++e) {
      int ul = u0l + e;
      int u = tile * 16 + ul;
      float gi = ldsG[0][ul][b2] + cd.bias[u];
      float gf = ldsG[1][ul][b2] + cd.bias[dh + u];
      float gg = ldsG[2][ul][b2] + cd.bias[2 * dh + u];
      float go = ldsG[3][ul][b2] + cd.bias[3 * dh + u];
      if (cd.pre) {
        const float* pb = cd.pre + (long)b2 * 4 * dh;
        gi += pb[u]; gf += pb[dh + u]; gg += pb[2 * dh + u]; go += pb[3 * dh + u];
      }
      float cold = cd.cbuf[(long)b2 * dh + u];
      float cn = sigm(gf) * cold + sigm(gi) * tanh_fast(gg);
      cv[e] = cn;
      float h = sigm(go) * tanh_fast(cn);
      hv[e] = h;
      sv[e] = sigm(h);
    }
    float4* cp = (float4*)(cd.cbuf + (long)b2 * dh + u0);
    cp[0] = make_float4(cv[0], cv[1], cv[2], cv[3]);
    cp[1] = make_float4(cv[4], cv[5], cv[6], cv[7]);
    const int ksh = dh >> 5;
    const int mt = b2 >> 4;
    const int kstep = u0 >> 5;
    const int lanep = (b2 & 15) + 16 * ((u0 >> 3) & 3);
    uint4 hp;
    hp.x = pack2bf(hv[0], hv[1]); hp.y = pack2bf(hv[2], hv[3]);
    hp.z = pack2bf(hv[4], hv[5]); hp.w = pack2bf(hv[6], hv[7]);
    ((uint4*)cd.hout)[((long)mt * ksh + kstep) * 64 + lanep] = hp;
    if (cd.sigout) {
      float4* sp = (float4*)(cd.sigout + (long)b2 * dh + u0);
      sp[0] = make_float4(sv[0], sv[1], sv[2], sv[3]);
      sp[1] = make_float4(sv[4], sv[5], sv[6], sv[7]);
    }
  }
}

// ------------------------------- host -----------------------------------------
extern "C" void kernel_launch(void* const* d_in, const int* in_sizes, int n_in,
                              void* d_out, int out_size, void* d_ws, size_t ws_size,
                              hipStream_t stream)
{
  const float* x_f = (const float*)d_in[0];
  const float* Wih[6]; const float* Whh[6]; const float* bias[6];
  for (int c = 0; c < 6; ++c) {
    Wih[c]  = (const float*)d_in[2 + 3 * c];
    Whh[c]  = (const float*)d_in[3 + 3 * c];
    bias[c] = (const float*)d_in[4 + 3 * c];
  }
  const int H = in_sizes[4] / 4;          // 1024
  const int D = in_sizes[2] / (4 * H);    // 4096
  const int B = 32;
  const int SB = in_sizes[0] / D;         // 640
  const int S = SB / B;                   // 20
  const int FUT = out_size / (B * D);     // 10
  (void)n_in; (void)ws_size;
  int klogH = 31 - __builtin_clz((unsigned)H);
  int klogD = 31 - __builtin_clz((unsigned)D);

  char* wsp = (char*)d_ws;
  size_t off = 0;
  auto alloc = [&](size_t bytes) -> void* {
    off = (off + 255) & ~(size_t)255;
    void* p = (void*)(wsp + off);
    off += bytes;
    return p;
  };

  const float* wsrc[11] = { Wih[0], Whh[0], Wih[1], Whh[1], Wih[2], Whh[2],
                            Whh[3], Wih[4], Whh[4], Wih[5], Whh[5] };
  long welems[11] = { (long)4*H*D, (long)4*H*H, (long)4*H*H, (long)4*H*H,
                      (long)4*H*H, (long)4*H*H, (long)4*H*H, (long)4*H*H,
                      (long)4*H*H, (long)4*D*H, (long)4*D*(long)D };
  int wrows[11] = { 4*H, 4*H, 4*H, 4*H, 4*H, 4*H, 4*H, 4*H, 4*H, 4*D, 4*D };
  int wklog[11] = { klogD, klogH, klogH, klogH, klogH, klogH,
                    klogH, klogH, klogH, klogH, klogD };
  u16* wb[11];
  for (int i = 0; i < 11; ++i) wb[i] = (u16*)alloc((size_t)welems[i] * 2);
  u16* xbf = (u16*)alloc((size_t)SB * D * 2);
  float* xpre = (float*)alloc((size_t)SB * D * 4);

  size_t zbeg = (off + 255) & ~(size_t)255;
  int* cnt = (int*)alloc(3 * 256 * 4);
  u16* eh[3][2]; u16* dhh[3][2];
  for (int c = 0; c < 3; ++c)
    for (int pp = 0; pp < 2; ++pp) eh[c][pp] = (u16*)alloc((size_t)B * H * 2);
  for (int c = 0; c < 2; ++c)
    for (int pp = 0; pp < 2; ++pp) dhh[c][pp] = (u16*)alloc((size_t)B * H * 2);
  for (int pp = 0; pp < 2; ++pp) dhh[2][pp] = (u16*)alloc((size_t)B * D * 2);
  float* ec[3]; float* dc[3];
  for (int c = 0; c < 3; ++c) ec[c] = (float*)alloc((size_t)B * H * 4);
  dc[0] = (float*)alloc((size_t)B * H * 4);
  dc[1] = (float*)alloc((size_t)B * H * 4);
  dc[2] = (float*)alloc((size_t)B * D * 4);
  size_t zend = off;

  const long PARTSTRIDE = (long)256 * 8 * 4 * 512;   // floats per cell slot region
  float* part = (float*)alloc((size_t)3 * PARTSTRIDE * 4);

  hipMemsetAsync((void*)(wsp + zbeg), 0, zend - zbeg, stream);

  // ---- upfront conversion: encoder weights (wsrc[0..5]) + x ----
  PKArgs pa;
  int cum = 0;
  for (int i = 0; i < 7; ++i) {
    int rows, klog;
    if (i < 6) { rows = wrows[i]; klog = wklog[i]; pa.src[i] = wsrc[i]; pa.dst[i] = (uint4*)wb[i]; }
    else       { rows = SB;       klog = klogD;    pa.src[i] = x_f;     pa.dst[i] = (uint4*)xbf; }
    int ns = 1 << (klog - 10);
    pa.cum[i] = cum;
    pa.nspan[i] = ns;
    pa.klog[i] = klog;
    cum += (rows / 8) * ns;
  }
  for (int i = 7; i <= NPK; ++i) pa.cum[i] = cum;
  cvt_pack<<<dim3(cum), dim3(256), 0, stream>>>(pa);

  gemm_pre<<<dim3(SB / 64, (4 * H) / 64), dim3(256), 0, stream>>>(xbf, wb[0], xpre, 4 * H, D);

  // ---- ride-along conversion jobs: decoder weights (wsrc[6..10]) ----
  PKRide ride;
  int rcum = 0;
  for (int i = 0; i < 5; ++i) {
    int wi = 6 + i;
    ride.src[i] = wsrc[wi];
    ride.dst[i] = (uint4*)wb[wi];
    int ns = 1 << (wklog[wi] - 10);
    ride.cum[i] = rcum;
    ride.nspan[i] = ns;
    ride.klog[i] = wklog[wi];
    rcum += (wrows[wi] / 8) * ns;
  }
  ride.cum[5] = rcum;
  const int nEnc = S + 2;
  const int per = (rcum + nEnc - 1) / nEnc;

  float* outp = (float*)d_out;

  auto mkcell = [&](const u16* A1, const u16* W1, int K1,
                    const u16* A2, const u16* W2, int K2,
                    const float* pre, const float* bs,
                    float* cb, u16* ho, float* so,
                    int dh, int nslog, int chunk, int pi) -> CellDesc {
    CellDesc cd;
    cd.A1 = A1; cd.W1 = W1; cd.K1 = K1;
    cd.A2 = A2; cd.W2 = W2; cd.K2 = K2;
    cd.pre = pre; cd.bias = bs;
    cd.cbuf = cb; cd.hout = ho; cd.sigout = so;
    cd.part = part + (long)pi * PARTSTRIDE;
    cd.cnt = cnt + pi * 256;
    cd.dh = dh; cd.chunk = chunk; cd.nslog = nslog; cd.blkend = 0;
    return cd;
  };

  // ---- encoder diagonals (with decoder-weight conversion ride-along) ----
  for (int d = 0; d < S + 2; ++d) {
    DiagArgs da; int nc = 0; int blk = 0;
    int t = d;
    if (t < S) {
      CellDesc cd = mkcell(eh[0][t & 1], wb[1], H, nullptr, nullptr, 0,
                           xpre + (long)t * B * 4 * H, bias[0],
                           ec[0], eh[0][(t + 1) & 1], nullptr, H, 2, H / 4, 0);
      blk += (H / 16) * 4; cd.blkend = blk; da.c[nc++] = cd;
    }
    t = d - 1;
    if (t >= 0 && t < S) {
      CellDesc cd = mkcell(eh[0][(t + 1) & 1], wb[2], H, eh[1][t & 1], wb[3], H,
                           nullptr, bias[1],
                           ec[1], eh[1][(t + 1) & 1], nullptr, H, 2, (2 * H) / 4, 1);
      blk += (H / 16) * 4; cd.blkend = blk; da.c[nc++] = cd;
    }
    t = d - 2;
    if (t >= 0 && t < S) {
      CellDesc cd = mkcell(eh[1][(t + 1) & 1], wb[4], H, eh[2][t & 1], wb[5], H,
                           nullptr, bias[2],
                           ec[2], eh[2][(t + 1) & 1], nullptr, H, 2, (2 * H) / 4, 2);
      blk += (H / 16) * 4; cd.blkend = blk; da.c[nc++] = cd;
    }
    da.ncell = nc;
    da.lstm_blocks = blk;
    int rs = d * per;
    int rc = rcum - rs;
    if (rc < 0) rc = 0;
    if (rc > per) rc = per;
    da.ride_start = rs;
    da.ride_count = rc;
    da.ride = ride;
    lstm_diag<<<dim3(blk + rc), dim3(256), 0, stream>>>(da);
  }
  const u16* ehfinal = eh[2][S & 1];

  // ---- decoder diagonals ----
  for (int d = 0; d < FUT + 2; ++d) {
    DiagArgs da; int nc = 0; int blk = 0;
    int t = d;
    if (t < FUT) {
      const u16* hprev = (t == 0) ? ehfinal : dhh[0][t & 1];
      CellDesc cd = mkcell(hprev, wb[6], H, nullptr, nullptr, 0,
                           nullptr, bias[3],
                           dc[0], dhh[0][(t + 1) & 1], nullptr, H, 2, H / 4, 0);
      blk += (H / 16) * 4; cd.blkend = blk; da.c[nc++] = cd;
    }
    t = d - 1;
    if (t >= 0 && t < FUT) {
      CellDesc cd = mkcell(dhh[0][(t + 1) & 1], wb[7], H, dhh[1][t & 1], wb[8], H,
                           nullptr, bias[4],
                           dc[1], dhh[1][(t + 1) & 1], nullptr, H, 2, (2 * H) / 4, 1);
      blk += (H / 16) * 4; cd.blkend = blk; da.c[nc++] = cd;
    }
    t = d - 2;
    if (t >= 0 && t < FUT) {
      CellDesc cd = mkcell(dhh[1][(t + 1) & 1], wb[9], H, dhh[2][t & 1], wb[10], D,
                           nullptr, bias[5],
                           dc[2], dhh[2][(t + 1) & 1], outp + (long)t * B * D,
                           D, 2, (H + D) / 4, 2);
      blk += (D / 16) * 4; cd.blkend = blk; da.c[nc++] = cd;
    }
    da.ncell = nc;
    da.lstm_blocks = blk;
    da.ride_start = 0;
    da.ride_count = 0;
    da.ride = ride;
    lstm_diag<<<dim3(blk), dim3(256), 0, stream>>>(da);
  }
}